// Round 1
// baseline (4227.594 us; speedup 1.0000x reference)
//
#include <hip/hip_runtime.h>
#include <math.h>

// Problem constants (from reference): T=2048, B=256, H=128, IN_DIM=1, NUM_DATA=4096
#define T_STEPS 2048
#define BATCH   256
#define HDIM    128

__device__ __forceinline__ float sigmoid_f(float x) {
    return 1.0f / (1.0f + __expf(-x));
}
__device__ __forceinline__ float tanh_f(float x) {
    // exact identity; saturates correctly for |x| large (exp->inf/0)
    float e = __expf(2.0f * x);
    return 1.0f - 2.0f / (e + 1.0f);
}

// One block per batch element (256 blocks -> one per CU). 256 threads.
// Thread t owns W_hh rows t and t+256 in registers (i/f and g/o gate rows).
__global__ __launch_bounds__(256, 1)
void lstm_seq_kernel(const int*   __restrict__ label,
                     const float* __restrict__ h0,     // (1, 4096, 128)
                     const float* __restrict__ W_ih,   // (512, 1)
                     const float* __restrict__ W_hh,   // (512, 128)
                     const float* __restrict__ b_ih,   // (512,)
                     const float* __restrict__ b_hh,   // (512,)
                     const float* __restrict__ W_lin,  // (1, 128)
                     const float* __restrict__ b_lin,  // (1,)
                     float*       __restrict__ out)    // (T, B, 1)
{
    const int tid   = threadIdx.x;
    const int batch = blockIdx.x;

    __shared__ float h_lds[HDIM];
    __shared__ float iact[HDIM], fact[HDIM], gact[HDIM], oact[HDIM];
    __shared__ float part[2];

    const int j0 = tid;        // rows 0..255   : i (0..127), f (128..255)
    const int j1 = tid + 256;  // rows 256..511 : g (256..383), o (384..511)

    // ---- one-time: load this thread's two W_hh rows into registers ----
    float4 w0[32], w1[32];
    const float4* W4 = (const float4*)W_hh;  // row j = W4[j*32 .. j*32+31]
    #pragma unroll
    for (int k = 0; k < 32; ++k) {
        w0[k] = W4[j0 * 32 + k];
        w1[k] = W4[j1 * 32 + k];
    }
    const float wih0  = W_ih[j0];
    const float wih1  = W_ih[j1];
    const float bias0 = b_ih[j0] + b_hh[j0];
    const float bias1 = b_ih[j1] + b_hh[j1];
    const float blin  = b_lin[0];
    const float wlin  = (tid < HDIM) ? W_lin[tid] : 0.0f;

    float c = 0.0f;
    if (tid < HDIM) {
        const int lab = label[batch];
        h_lds[tid] = h0[lab * HDIM + tid];
    }
    __syncthreads();

    const float4* h4 = (const float4*)h_lds;
    float x = 0.0f;  // t=0 input is zeros

    for (int t = 0; t < T_STEPS; ++t) {
        // ---------------- Phase A: gate GEMV (2 rows/thread) ----------------
        float a0 = fmaf(x, wih0, bias0);
        float a1 = fmaf(x, wih1, bias1);
        float c0 = 0.0f, c1 = 0.0f;  // second accumulator pair (odd chunks)
        #pragma unroll
        for (int k = 0; k < 32; k += 2) {
            float4 hv = h4[k];
            a0 = fmaf(hv.x, w0[k].x, a0);
            a1 = fmaf(hv.x, w1[k].x, a1);
            a0 = fmaf(hv.y, w0[k].y, a0);
            a1 = fmaf(hv.y, w1[k].y, a1);
            a0 = fmaf(hv.z, w0[k].z, a0);
            a1 = fmaf(hv.z, w1[k].z, a1);
            a0 = fmaf(hv.w, w0[k].w, a0);
            a1 = fmaf(hv.w, w1[k].w, a1);
            float4 hw = h4[k + 1];
            c0 = fmaf(hw.x, w0[k + 1].x, c0);
            c1 = fmaf(hw.x, w1[k + 1].x, c1);
            c0 = fmaf(hw.y, w0[k + 1].y, c0);
            c1 = fmaf(hw.y, w1[k + 1].y, c1);
            c0 = fmaf(hw.z, w0[k + 1].z, c0);
            c1 = fmaf(hw.z, w1[k + 1].z, c1);
            c0 = fmaf(hw.w, w0[k + 1].w, c0);
            c1 = fmaf(hw.w, w1[k + 1].w, c1);
        }
        const float g0 = a0 + c0;  // gate for row j0
        const float g1 = a1 + c1;  // gate for row j1

        if (tid < HDIM) {
            iact[tid] = sigmoid_f(g0);   // rows 0..127   = i
            gact[tid] = tanh_f(g1);      // rows 256..383 = g
        } else {
            fact[tid - HDIM] = sigmoid_f(g0);  // rows 128..255 = f
            oact[tid - HDIM] = sigmoid_f(g1);  // rows 384..511 = o
        }
        __syncthreads();

        // ---------------- Phase B: cell/hidden update + y reduction ----------
        if (tid < HDIM) {
            const float cn = fmaf(fact[tid], c, iact[tid] * gact[tid]);
            c = cn;
            const float hn = oact[tid] * tanh_f(cn);
            h_lds[tid] = hn;
            float p = hn * wlin;
            #pragma unroll
            for (int off = 32; off > 0; off >>= 1)
                p += __shfl_xor(p, off, 64);
            if ((tid & 63) == 0) part[tid >> 6] = p;
        }
        __syncthreads();

        // all threads recompute next x from the two partials (LDS broadcast)
        x = (part[0] + part[1]) + blin;
        if (tid == 0) out[t * BATCH + batch] = x;
    }
}

extern "C" void kernel_launch(void* const* d_in, const int* in_sizes, int n_in,
                              void* d_out, int out_size, void* d_ws, size_t ws_size,
                              hipStream_t stream) {
    // inputs: 0 input (unused data), 1 label, 2 h0, 3 W_ih, 4 W_hh,
    //         5 b_ih, 6 b_hh, 7 W_lin, 8 b_lin
    const int*   label = (const int*)  d_in[1];
    const float* h0    = (const float*)d_in[2];
    const float* W_ih  = (const float*)d_in[3];
    const float* W_hh  = (const float*)d_in[4];
    const float* b_ih  = (const float*)d_in[5];
    const float* b_hh  = (const float*)d_in[6];
    const float* W_lin = (const float*)d_in[7];
    const float* b_lin = (const float*)d_in[8];
    float* out = (float*)d_out;

    lstm_seq_kernel<<<dim3(BATCH), dim3(256), 0, stream>>>(
        label, h0, W_ih, W_hh, b_ih, b_hh, W_lin, b_lin, out);
}

// Round 2
// 2286.182 us; speedup vs baseline: 1.8492x; 1.8492x over previous
//
#include <hip/hip_runtime.h>
#include <math.h>

// Problem constants: T=2048, B=256, H=128, IN_DIM=1, NUM_DATA=4096
#define T_STEPS 2048
#define BATCH   256
#define HDIM    128

// Fast activations: v_exp_f32 + v_rcp_f32. Error ~1 ulp; output margin is
// huge (absmax 0.0 vs 4.8e-4 threshold in R0 with exact division).
__device__ __forceinline__ float fast_rcp(float x) {
    return __builtin_amdgcn_rcpf(x);
}
__device__ __forceinline__ float sigmoid_f(float x) {
    return fast_rcp(1.0f + __expf(-x));
}
__device__ __forceinline__ float tanh_f(float x) {
    float e = __expf(2.0f * x);
    return 1.0f - 2.0f * fast_rcp(e + 1.0f);
}

// One block per batch element (256 blocks -> 1 per CU). 512 threads = 8 waves
// = 2 waves/SIMD. Thread t owns W_hh row t in registers (128 floats = 32
// float4 = 128 VGPRs; total ~180 VGPR/thread, fits the 256-VGPR cap at
// 2 waves/EU -> NO spill, unlike R0's 2-rows/thread layout).
// Gate rows: i = 0..127 (waves 0-1), f = 128..255 (waves 2-3),
//            g = 256..383 (waves 4-5), o = 384..511 (waves 6-7).
// Activation branches are wave-uniform.
__global__ __launch_bounds__(512, 2)
void lstm_seq_kernel(const int*   __restrict__ label,
                     const float* __restrict__ h0,     // (1, 4096, 128)
                     const float* __restrict__ W_ih,   // (512, 1)
                     const float* __restrict__ W_hh,   // (512, 128)
                     const float* __restrict__ b_ih,   // (512,)
                     const float* __restrict__ b_hh,   // (512,)
                     const float* __restrict__ W_lin,  // (1, 128)
                     const float* __restrict__ b_lin,  // (1,)
                     float*       __restrict__ out)    // (T, B, 1)
{
    const int tid   = threadIdx.x;
    const int batch = blockIdx.x;

    __shared__ float h_lds[HDIM];
    __shared__ float act[4 * HDIM];   // activated gates, indexed by row id
    __shared__ float part[2];

    // ---- one-time: this thread's W_hh row into registers ----
    float4 w[32];
    const float4* W4 = (const float4*)W_hh;  // row j = W4[j*32 .. j*32+31]
    #pragma unroll
    for (int k = 0; k < 32; ++k) w[k] = W4[tid * 32 + k];

    const float wih  = W_ih[tid];
    const float bias = b_ih[tid] + b_hh[tid];
    const float blin = b_lin[0];
    const float wlin = (tid < HDIM) ? W_lin[tid] : 0.0f;

    float c = 0.0f;
    if (tid < HDIM) {
        const int lab = label[batch];
        h_lds[tid] = h0[lab * HDIM + tid];
    }
    __syncthreads();

    const float4* h4 = (const float4*)h_lds;
    float x = 0.0f;  // t=0 input is zeros

    for (int t = 0; t < T_STEPS; ++t) {
        // ---------- Phase A: one gate value per thread (128 FMAs) ----------
        float a0 = fmaf(x, wih, bias);
        float a1 = 0.0f, a2 = 0.0f, a3 = 0.0f;  // 4 independent chains
        #pragma unroll
        for (int k = 0; k < 32; k += 4) {
            float4 h0v = h4[k];
            float4 h1v = h4[k + 1];
            float4 h2v = h4[k + 2];
            float4 h3v = h4[k + 3];
            a0 = fmaf(h0v.x, w[k].x, a0);
            a0 = fmaf(h0v.y, w[k].y, a0);
            a0 = fmaf(h0v.z, w[k].z, a0);
            a0 = fmaf(h0v.w, w[k].w, a0);
            a1 = fmaf(h1v.x, w[k + 1].x, a1);
            a1 = fmaf(h1v.y, w[k + 1].y, a1);
            a1 = fmaf(h1v.z, w[k + 1].z, a1);
            a1 = fmaf(h1v.w, w[k + 1].w, a1);
            a2 = fmaf(h2v.x, w[k + 2].x, a2);
            a2 = fmaf(h2v.y, w[k + 2].y, a2);
            a2 = fmaf(h2v.z, w[k + 2].z, a2);
            a2 = fmaf(h2v.w, w[k + 2].w, a2);
            a3 = fmaf(h3v.x, w[k + 3].x, a3);
            a3 = fmaf(h3v.y, w[k + 3].y, a3);
            a3 = fmaf(h3v.z, w[k + 3].z, a3);
            a3 = fmaf(h3v.w, w[k + 3].w, a3);
        }
        const float gate = (a0 + a1) + (a2 + a3);

        // wave-uniform activation selection
        float v;
        if (tid < 256)       v = sigmoid_f(gate);  // i, f
        else if (tid < 384)  v = tanh_f(gate);     // g
        else                 v = sigmoid_f(gate);  // o
        act[tid] = v;
        __syncthreads();

        // ---------- Phase B: cell/hidden update + y reduction (waves 0-1) ----
        if (tid < HDIM) {
            const float iv = act[tid];
            const float fv = act[HDIM + tid];
            const float gv = act[2 * HDIM + tid];
            const float ov = act[3 * HDIM + tid];
            const float cn = fmaf(fv, c, iv * gv);
            c = cn;
            const float hn = ov * tanh_f(cn);
            h_lds[tid] = hn;
            float p = hn * wlin;
            #pragma unroll
            for (int off = 32; off > 0; off >>= 1)
                p += __shfl_xor(p, off, 64);
            if ((tid & 63) == 0) part[tid >> 6] = p;
        }
        __syncthreads();

        // all threads compute next x from the two wave partials
        x = (part[0] + part[1]) + blin;
        if (tid == 0) out[t * BATCH + batch] = x;
    }
}

extern "C" void kernel_launch(void* const* d_in, const int* in_sizes, int n_in,
                              void* d_out, int out_size, void* d_ws, size_t ws_size,
                              hipStream_t stream) {
    // inputs: 0 input (unused data), 1 label, 2 h0, 3 W_ih, 4 W_hh,
    //         5 b_ih, 6 b_hh, 7 W_lin, 8 b_lin
    const int*   label = (const int*)  d_in[1];
    const float* h0    = (const float*)d_in[2];
    const float* W_ih  = (const float*)d_in[3];
    const float* W_hh  = (const float*)d_in[4];
    const float* b_ih  = (const float*)d_in[5];
    const float* b_hh  = (const float*)d_in[6];
    const float* W_lin = (const float*)d_in[7];
    const float* b_lin = (const float*)d_in[8];
    float* out = (float*)d_out;

    lstm_seq_kernel<<<dim3(BATCH), dim3(512), 0, stream>>>(
        label, h0, W_ih, W_hh, b_ih, b_hh, W_lin, b_lin, out);
}

// Round 3
// 2097.386 us; speedup vs baseline: 2.0156x; 1.0900x over previous
//
#include <hip/hip_runtime.h>
#include <math.h>

// Problem constants: T=2048, B=256, H=128, IN_DIM=1, NUM_DATA=4096
#define T_STEPS 2048
#define BATCH   256
#define HDIM    128

__device__ __forceinline__ float fast_rcp(float x) { return __builtin_amdgcn_rcpf(x); }
__device__ __forceinline__ float sigmoid_f(float x) { return fast_rcp(1.0f + __expf(-x)); }
__device__ __forceinline__ float tanh_f(float x) {
    float e = __expf(2.0f * x);
    return 1.0f - 2.0f * fast_rcp(e + 1.0f);
}

#define REP16(M) M(0) M(1) M(2) M(3) M(4) M(5) M(6) M(7) \
                 M(8) M(9) M(10) M(11) M(12) M(13) M(14) M(15)

// One block per batch element (256 blocks -> 1/CU), 512 threads = 8 waves =
// 2 waves/SIMD. Threads (2p, 2p+1) jointly own gate rows 2p and 2p+1:
// even thread covers h[0:64), odd thread h[64:128) (so row index == tid).
// 32 NAMED float4 weight regs per thread (128 VGPRs), pinned with empty asm
// so the compiler can neither spill-remat nor sink the loads into the loop
// (R2's VGPR_Count=80 showed exactly that pathology).
//
// Feedback fold: x_t = h_{t-1}.W_lin + b_lin for t>=1, so
//   gates_t = h_{t-1}.(W_hh + W_ih (x) W_lin)^T + (b + W_ih*b_lin)
// The scalar y never enters the critical path; t=0 (x=0) is fixed by
// subtracting wih*y_init from the bias on the first iteration only.
__global__ __launch_bounds__(512, 2)
void lstm_seq_kernel(const int*   __restrict__ label,
                     const float* __restrict__ h0,     // (1, 4096, 128)
                     const float* __restrict__ W_ih,   // (512, 1)
                     const float* __restrict__ W_hh,   // (512, 128)
                     const float* __restrict__ b_ih,   // (512,)
                     const float* __restrict__ b_hh,   // (512,)
                     const float* __restrict__ W_lin,  // (1, 128)
                     const float* __restrict__ b_lin,  // (1,)
                     float*       __restrict__ out)    // (T, B, 1)
{
    const int tid   = threadIdx.x;
    const int batch = blockIdx.x;
    const int hsel  = tid & 1;       // 0: k in [0,64), 1: k in [64,128)
    const int r0    = tid & ~1;      // even row of this pair
    const int r1    = tid | 1;       // odd row of this pair

    __shared__ float4 h4s[HDIM / 4];     // h, 16B-aligned for b128 reads
    __shared__ float  act[4 * HDIM];     // activated gates, index = row
    __shared__ float  part[2];
    float* h_lds = (float*)h4s;

    const float4* W4 = (const float4*)W_hh;   // row j = W4[j*32 ..]
    const float4* L4 = (const float4*)W_lin;  // 32 float4
    const int wbase0 = r0 * 32 + hsel * 16;
    const int wbase1 = r1 * 32 + hsel * 16;
    const int lbase  = hsel * 16;

    // ---- load W_hh rows into 32 named float4s ----
    #define DECL_W(i) float4 wa##i = W4[wbase0 + (i)]; float4 wb##i = W4[wbase1 + (i)];
    REP16(DECL_W)

    const float wihr0 = W_ih[r0];
    const float wihr1 = W_ih[r1];
    const float blin  = b_lin[0];
    const float wlin  = (tid < HDIM) ? W_lin[tid] : 0.0f;
    const float biasP0 = b_ih[r0] + b_hh[r0] + wihr0 * blin;
    const float biasP1 = b_ih[r1] + b_hh[r1] + wihr1 * blin;

    // ---- fold feedback: W' = W_hh + wih (x) W_lin ----
    #define FOLD_W(i) { float4 lv = L4[lbase + (i)]; \
        wa##i.x = fmaf(wihr0, lv.x, wa##i.x); wa##i.y = fmaf(wihr0, lv.y, wa##i.y); \
        wa##i.z = fmaf(wihr0, lv.z, wa##i.z); wa##i.w = fmaf(wihr0, lv.w, wa##i.w); \
        wb##i.x = fmaf(wihr1, lv.x, wb##i.x); wb##i.y = fmaf(wihr1, lv.y, wb##i.y); \
        wb##i.z = fmaf(wihr1, lv.z, wb##i.z); wb##i.w = fmaf(wihr1, lv.w, wb##i.w); }
    REP16(FOLD_W)

    // ---- pin: opaque defs -> no remat, no sinking into the loop ----
    #define PIN_W(i) asm("" : "+v"(wa##i.x), "+v"(wa##i.y), "+v"(wa##i.z), "+v"(wa##i.w), \
                              "+v"(wb##i.x), "+v"(wb##i.y), "+v"(wb##i.z), "+v"(wb##i.w));
    REP16(PIN_W)

    float c = 0.0f;
    if (tid < HDIM) h_lds[tid] = h0[label[batch] * HDIM + tid];
    __syncthreads();

    // y_init = h_init . W_lin + b_lin (needed for the t=0 bias correction)
    if (tid < HDIM) {
        float p = h_lds[tid] * wlin;
        #pragma unroll
        for (int off = 32; off > 0; off >>= 1) p += __shfl_xor(p, off, 64);
        if ((tid & 63) == 0) part[tid >> 6] = p;
    }
    __syncthreads();
    const float y0 = part[0] + part[1] + blin;

    float bb0 = biasP0 - wihr0 * y0;   // first-iteration bias (x_0 = 0)
    float bb1 = biasP1 - wihr1 * y0;

    for (int t = 0; t < T_STEPS; ++t) {
        // write last step's y (part[] made visible by the closing barrier)
        if (tid == 0 && t > 0) out[(t - 1) * BATCH + batch] = part[0] + part[1] + blin;

        // ---------- Phase A: two half-row dots per thread ----------
        float a0 = hsel ? 0.0f : bb0;   // bias added once per row (even thread)
        float a1 = hsel ? 0.0f : bb1;
        float d0 = 0.0f, d1 = 0.0f;     // 4 independent FMA chains
        #define DOTP(i, j) { \
            float4 hv = h4s[lbase + (i)]; \
            float4 hw = h4s[lbase + (j)]; \
            a0 = fmaf(hv.x, wa##i.x, a0); a1 = fmaf(hv.x, wb##i.x, a1); \
            a0 = fmaf(hv.y, wa##i.y, a0); a1 = fmaf(hv.y, wb##i.y, a1); \
            a0 = fmaf(hv.z, wa##i.z, a0); a1 = fmaf(hv.z, wb##i.z, a1); \
            a0 = fmaf(hv.w, wa##i.w, a0); a1 = fmaf(hv.w, wb##i.w, a1); \
            d0 = fmaf(hw.x, wa##j.x, d0); d1 = fmaf(hw.x, wb##j.x, d1); \
            d0 = fmaf(hw.y, wa##j.y, d0); d1 = fmaf(hw.y, wb##j.y, d1); \
            d0 = fmaf(hw.z, wa##j.z, d0); d1 = fmaf(hw.z, wb##j.z, d1); \
            d0 = fmaf(hw.w, wa##j.w, d0); d1 = fmaf(hw.w, wb##j.w, d1); }
        DOTP(0, 1)  DOTP(2, 3)  DOTP(4, 5)  DOTP(6, 7)
        DOTP(8, 9)  DOTP(10, 11) DOTP(12, 13) DOTP(14, 15)

        float g0 = a0 + d0;                 // partial of row r0 (this half)
        float g1 = a1 + d1;                 // partial of row r1 (this half)
        g0 += __shfl_xor(g0, 1, 64);        // combine halves within the pair
        g1 += __shfl_xor(g1, 1, 64);
        const float pre = hsel ? g1 : g0;   // this thread's own row == tid

        // gate type by row block (wave-uniform: boundaries at 128-row marks)
        const int gt = tid >> 7;            // 0=i 1=f 2=g 3=o
        act[tid] = (gt == 2) ? tanh_f(pre) : sigmoid_f(pre);
        __syncthreads();

        // ---------- Phase B: cell/hidden update + deferred y ----------
        if (tid < HDIM) {
            const float iv = act[tid];
            const float fv = act[HDIM + tid];
            const float gv = act[2 * HDIM + tid];
            const float ov = act[3 * HDIM + tid];
            c = fmaf(fv, c, iv * gv);
            const float hn = ov * tanh_f(c);
            h_lds[tid] = hn;
            float p = hn * wlin;            // y_t partial (NOT on critical path)
            #pragma unroll
            for (int off = 32; off > 0; off >>= 1) p += __shfl_xor(p, off, 64);
            if ((tid & 63) == 0) part[tid >> 6] = p;
        }
        __syncthreads();

        bb0 = biasP0;  bb1 = biasP1;        // drop t=0 correction after iter 0
    }

    if (tid == 0) out[(T_STEPS - 1) * BATCH + batch] = part[0] + part[1] + blin;
}

extern "C" void kernel_launch(void* const* d_in, const int* in_sizes, int n_in,
                              void* d_out, int out_size, void* d_ws, size_t ws_size,
                              hipStream_t stream) {
    // inputs: 0 input (unused), 1 label, 2 h0, 3 W_ih, 4 W_hh,
    //         5 b_ih, 6 b_hh, 7 W_lin, 8 b_lin
    const int*   label = (const int*)  d_in[1];
    const float* h0    = (const float*)d_in[2];
    const float* W_ih  = (const float*)d_in[3];
    const float* W_hh  = (const float*)d_in[4];
    const float* b_ih  = (const float*)d_in[5];
    const float* b_hh  = (const float*)d_in[6];
    const float* W_lin = (const float*)d_in[7];
    const float* b_lin = (const float*)d_in[8];
    float* out = (float*)d_out;

    lstm_seq_kernel<<<dim3(BATCH), dim3(512), 0, stream>>>(
        label, h0, W_ih, W_hh, b_ih, b_hh, W_lin, b_lin, out);
}

// Round 5
// 2087.258 us; speedup vs baseline: 2.0254x; 1.0049x over previous
//
#include <hip/hip_runtime.h>
#include <math.h>

// Problem constants: T=2048, B=256, H=128, IN_DIM=1, NUM_DATA=4096
#define T_STEPS 2048
#define BATCH   256
#define HDIM    128

__device__ __forceinline__ float fast_rcp(float x) { return __builtin_amdgcn_rcpf(x); }
__device__ __forceinline__ float sigmoid_f(float x) { return fast_rcp(1.0f + __expf(-x)); }
__device__ __forceinline__ float tanh_f(float x) {
    float e = __expf(2.0f * x);
    return 1.0f - 2.0f * fast_rcp(e + 1.0f);
}

#define REP16(M) M(0) M(1) M(2) M(3) M(4) M(5) M(6) M(7) \
                 M(8) M(9) M(10) M(11) M(12) M(13) M(14) M(15)

// One block per batch element (256 blocks -> 1/CU), 512 threads = 8 waves =
// 2 waves/SIMD. Threads (2p, 2p+1) jointly own gate rows 2p and 2p+1:
// even thread covers h[0:64), odd thread h[64:128).
//
// R4 bug fixed here: waves 2-3's y-reduction wrote part[(tid-256)>>6] with
// tid in [128,256) -> part[-2]/part[-1] (OOB into act[] + stale part[]).
// Correct index is (tid - HDIM) >> 6.
//
// R3 lessons baked in:
//  * asm pins are VOLATILE (non-volatile asm is pure -> compiler sank the
//    weight loads into the loop; VGPR_Count stayed 80).
//  * h is stored split with a 16-word gap so even-lane reads (words 4i) and
//    odd-lane reads (words 80+4i) hit DISJOINT bank groups (R3 had 2.7e8
//    bank-conflict cycles from both halves aliasing banks 4i..4i+3).
//  * waves 2-3 mirror the c/h update redundantly and own the y-reduction,
//    so waves 0-1 only update c and publish h (shorter serial tail).
//
// Feedback fold (verified absmax 0.0 in R3): x_t = h_{t-1}.W_lin + b_lin =>
//   gates_t = h_{t-1}.(W_hh + W_ih (x) W_lin)^T + (b + W_ih*b_lin),
// t=0 corrected by subtracting wih*y_init from the bias on iteration 0.
__global__ __launch_bounds__(512, 2) __attribute__((amdgpu_waves_per_eu(2, 2)))
void lstm_seq_kernel(const int*   __restrict__ label,
                     const float* __restrict__ h0,     // (1, 4096, 128)
                     const float* __restrict__ W_ih,   // (512, 1)
                     const float* __restrict__ W_hh,   // (512, 128)
                     const float* __restrict__ b_ih,   // (512,)
                     const float* __restrict__ b_hh,   // (512,)
                     const float* __restrict__ W_lin,  // (1, 128)
                     const float* __restrict__ b_lin,  // (1,)
                     float*       __restrict__ out)    // (T, B, 1)
{
    const int tid   = threadIdx.x;
    const int batch = blockIdx.x;
    const int hsel  = tid & 1;       // 0: k in [0,64), 1: k in [64,128)
    const int r0    = tid & ~1;      // even row of this pair
    const int r1    = tid | 1;       // odd row of this pair

    // h split layout: h[k] at word k (k<64) or word k+16 (k>=64).
    // Even lanes read words 4i..4i+3, odd lanes words 80+4i -> disjoint
    // bank groups, zero conflicts.
    __shared__ float h_lds[160];
    __shared__ float act[4 * HDIM];     // activated gates, index = row
    __shared__ float part[2];

    const float4* W4 = (const float4*)W_hh;   // row j = W4[j*32 ..]
    const float4* L4 = (const float4*)W_lin;  // 32 float4
    const int wbase0 = r0 * 32 + hsel * 16;
    const int wbase1 = r1 * 32 + hsel * 16;
    const int lbase  = hsel * 16;

    // ---- load W_hh rows into 32 named float4s ----
    #define DECL_W(i) float4 wa##i = W4[wbase0 + (i)]; float4 wb##i = W4[wbase1 + (i)];
    REP16(DECL_W)

    const float wihr0 = W_ih[r0];
    const float wihr1 = W_ih[r1];
    const float blin  = b_lin[0];
    const float wlin  = (tid < 2 * HDIM) ? W_lin[tid & (HDIM - 1)] : 0.0f;
    const float biasP0 = b_ih[r0] + b_hh[r0] + wihr0 * blin;
    const float biasP1 = b_ih[r1] + b_hh[r1] + wihr1 * blin;

    // ---- fold feedback: W' = W_hh + wih (x) W_lin ----
    #define FOLD_W(i) { float4 lv = L4[lbase + (i)]; \
        wa##i.x = fmaf(wihr0, lv.x, wa##i.x); wa##i.y = fmaf(wihr0, lv.y, wa##i.y); \
        wa##i.z = fmaf(wihr0, lv.z, wa##i.z); wa##i.w = fmaf(wihr0, lv.w, wa##i.w); \
        wb##i.x = fmaf(wihr1, lv.x, wb##i.x); wb##i.y = fmaf(wihr1, lv.y, wb##i.y); \
        wb##i.z = fmaf(wihr1, lv.z, wb##i.z); wb##i.w = fmaf(wihr1, lv.w, wb##i.w); }
    REP16(FOLD_W)

    // ---- pin: VOLATILE opaque defs -> cannot be deleted, duplicated,
    //      rematerialized, or sunk into the loop ----
    #define PIN_W(i) asm volatile("" : "+v"(wa##i.x), "+v"(wa##i.y), "+v"(wa##i.z), "+v"(wa##i.w), \
                                       "+v"(wb##i.x), "+v"(wb##i.y), "+v"(wb##i.z), "+v"(wb##i.w));
    REP16(PIN_W)

    float c = 0.0f;
    const int hword = (tid & (HDIM - 1)) + ((tid & 64) ? 16 : 0);  // split addr
    if (tid < HDIM) h_lds[hword] = h0[label[batch] * HDIM + tid];
    __syncthreads();

    // y_init = h_init . W_lin + b_lin (for the t=0 bias correction)
    if (tid < HDIM) {
        float p = h_lds[hword] * wlin;
        #pragma unroll
        for (int off = 32; off > 0; off >>= 1) p += __shfl_xor(p, off, 64);
        if ((tid & 63) == 0) part[tid >> 6] = p;
    }
    __syncthreads();
    const float y0 = part[0] + part[1] + blin;

    float bb0 = biasP0 - wihr0 * y0;   // first-iteration bias (x_0 = 0)
    float bb1 = biasP1 - wihr1 * y0;

    const float4* hbase = (const float4*)(h_lds + hsel * 80);

    for (int t = 0; t < T_STEPS; ++t) {
        // write last step's y (part[] made visible by the closing barrier)
        if (tid == 0 && t > 0) out[(t - 1) * BATCH + batch] = part[0] + part[1] + blin;

        // ---------- Phase A: two half-row dots per thread ----------
        float a0 = hsel ? 0.0f : bb0;   // bias added once per row (even thread)
        float a1 = hsel ? 0.0f : bb1;
        float d0 = 0.0f, d1 = 0.0f;     // 4 independent FMA chains
        #define DOTP(i, j) { \
            float4 hv = hbase[(i)]; \
            float4 hw = hbase[(j)]; \
            a0 = fmaf(hv.x, wa##i.x, a0); a1 = fmaf(hv.x, wb##i.x, a1); \
            a0 = fmaf(hv.y, wa##i.y, a0); a1 = fmaf(hv.y, wb##i.y, a1); \
            a0 = fmaf(hv.z, wa##i.z, a0); a1 = fmaf(hv.z, wb##i.z, a1); \
            a0 = fmaf(hv.w, wa##i.w, a0); a1 = fmaf(hv.w, wb##i.w, a1); \
            d0 = fmaf(hw.x, wa##j.x, d0); d1 = fmaf(hw.x, wb##j.x, d1); \
            d0 = fmaf(hw.y, wa##j.y, d0); d1 = fmaf(hw.y, wb##j.y, d1); \
            d0 = fmaf(hw.z, wa##j.z, d0); d1 = fmaf(hw.z, wb##j.z, d1); \
            d0 = fmaf(hw.w, wa##j.w, d0); d1 = fmaf(hw.w, wb##j.w, d1); }
        DOTP(0, 1)  DOTP(2, 3)  DOTP(4, 5)  DOTP(6, 7)
        DOTP(8, 9)  DOTP(10, 11) DOTP(12, 13) DOTP(14, 15)

        float g0 = a0 + d0;                 // partial of row r0 (this half)
        float g1 = a1 + d1;                 // partial of row r1 (this half)
        g0 += __shfl_xor(g0, 1, 64);        // combine halves within the pair
        g1 += __shfl_xor(g1, 1, 64);
        const float pre = hsel ? g1 : g0;   // this thread's own row == tid

        // gate type by row block (wave-uniform: boundaries at 128-row marks)
        const int gt = tid >> 7;            // 0=i 1=f 2=g 3=o
        act[tid] = (gt == 2) ? tanh_f(pre) : sigmoid_f(pre);
        __syncthreads();

        // ---------- Phase B: waves 0-3 mirror the c/h update ----------
        if (tid < 2 * HDIM) {
            const int hh = tid & (HDIM - 1);
            const float iv = act[hh];
            const float fv = act[HDIM + hh];
            const float gv = act[2 * HDIM + hh];
            const float ov = act[3 * HDIM + hh];
            c = fmaf(fv, c, iv * gv);
            const float hn = ov * tanh_f(c);
            if (tid < HDIM) {
                h_lds[hword] = hn;          // waves 0-1: publish h
            } else {
                float p = hn * wlin;        // waves 2-3: y reduction
                #pragma unroll
                for (int off = 32; off > 0; off >>= 1) p += __shfl_xor(p, off, 64);
                if ((tid & 63) == 0) part[(tid - HDIM) >> 6] = p;  // R4 fix
            }
        }
        __syncthreads();

        bb0 = biasP0;  bb1 = biasP1;        // drop t=0 correction after iter 0
    }

    if (tid == 0) out[(T_STEPS - 1) * BATCH + batch] = part[0] + part[1] + blin;
}

extern "C" void kernel_launch(void* const* d_in, const int* in_sizes, int n_in,
                              void* d_out, int out_size, void* d_ws, size_t ws_size,
                              hipStream_t stream) {
    // inputs: 0 input (unused), 1 label, 2 h0, 3 W_ih, 4 W_hh,
    //         5 b_ih, 6 b_hh, 7 W_lin, 8 b_lin
    const int*   label = (const int*)  d_in[1];
    const float* h0    = (const float*)d_in[2];
    const float* W_ih  = (const float*)d_in[3];
    const float* W_hh  = (const float*)d_in[4];
    const float* b_ih  = (const float*)d_in[5];
    const float* b_hh  = (const float*)d_in[6];
    const float* W_lin = (const float*)d_in[7];
    const float* b_lin = (const float*)d_in[8];
    float* out = (float*)d_out;

    lstm_seq_kernel<<<dim3(BATCH), dim3(512), 0, stream>>>(
        label, h0, W_ih, W_hh, b_ih, b_hh, W_lin, b_lin, out);
}